// Round 6
// baseline (124.192 us; speedup 1.0000x reference)
//
#include <hip/hip_runtime.h>
#include <math.h>

#define NB 8192
#define NH 4096
#define TPB 256
#define ITERS ((NH / 4) / TPB)   // 4

// One block per row. Computes row stats and atomically adds this row's
// affine contribution to the scalar loss:
//   total = 0.25 + sum_rows [ 0.5*sse/(NB*NH) - 0.25*M/(NB*(NH-1))
//                             + 0.125*(1-corr)/NB ]
// out[0] is zeroed on-stream before launch; block 0 adds the 0.25 constant.
// 8192 float atomicAdds to one address spread over ~45us: negligible
// contention, no fences needed (atomics resolve at the coherence point).
__global__ __launch_bounds__(TPB) void row_loss_kernel(
    const float* __restrict__ pred, const float* __restrict__ targ,
    float* __restrict__ out)
{
    const int row = blockIdx.x;
    const float* p = pred + (size_t)row * NH;
    const float* t = targ + (size_t)row * NH;
    const int tid  = threadIdx.x;
    const int lane = tid & 63;
    const int wave = tid >> 6;

    const float4* p4 = (const float4*)p;
    const float4* t4 = (const float4*)t;

    // Hoist all loads: 8 outstanding float4 loads per thread (MLP).
    float4 pv[ITERS], tv[ITERS];
#pragma unroll
    for (int it = 0; it < ITERS; ++it) {
        pv[it] = p4[it * TPB + tid];
        tv[it] = t4[it * TPB + tid];
    }

    float Sp = 0.f, Spp = 0.f, St = 0.f, Stt = 0.f, Spt = 0.f;
    int M = 0;

#pragma unroll
    for (int it = 0; it < ITERS; ++it) {
        const int q = it * TPB + tid;
        const float4 P = pv[it];
        const float4 T = tv[it];

        Sp  += (P.x + P.y) + (P.z + P.w);
        St  += (T.x + T.y) + (T.z + T.w);
        Spp += (P.x * P.x + P.y * P.y) + (P.z * P.z + P.w * P.w);
        Stt += (T.x * T.x + T.y * T.y) + (T.z * T.z + T.w * T.w);
        Spt += (P.x * T.x + P.y * T.y) + (P.z * T.z + P.w * T.w);

        // prev element (index 4q-1): previous lane's .w; lane 0 re-loads
        // (L1/L2-hit, 2 scalar loads per wave per iter).
        float pprev = __shfl_up(P.w, 1);
        float tprev = __shfl_up(T.w, 1);
        if (lane == 0 && q > 0) { pprev = p[4 * q - 1]; tprev = t[4 * q - 1]; }

        // match = (dt == 0) | (dp*dt > 0); one flipped match moves the loss
        // by 3e-8 (threshold 2.5e-2).
        if (q > 0) {
            const float dp = P.x - pprev, dt = T.x - tprev;
            M += (dt == 0.f) | (dp * dt > 0.f);
        }
        {
            const float dp1 = P.y - P.x, dt1 = T.y - T.x;
            M += (dt1 == 0.f) | (dp1 * dt1 > 0.f);
            const float dp2 = P.z - P.y, dt2 = T.z - T.y;
            M += (dt2 == 0.f) | (dp2 * dt2 > 0.f);
            const float dp3 = P.w - P.z, dt3 = T.w - T.z;
            M += (dt3 == 0.f) | (dp3 * dt3 > 0.f);
        }
    }

    // 64-lane wave reduce.
    float fM = (float)M;   // per-thread M <= 16, wave sum <= 1024: exact fp32
#pragma unroll
    for (int off = 32; off > 0; off >>= 1) {
        Sp  += __shfl_down(Sp, off);
        Spp += __shfl_down(Spp, off);
        St  += __shfl_down(St, off);
        Stt += __shfl_down(Stt, off);
        Spt += __shfl_down(Spt, off);
        fM  += __shfl_down(fM, off);
    }

    __shared__ float red[4][6];
    if (lane == 0) {
        red[wave][0] = Sp;  red[wave][1] = Spp; red[wave][2] = St;
        red[wave][3] = Stt; red[wave][4] = Spt; red[wave][5] = fM;
    }
    __syncthreads();
    if (tid == 0) {
        Sp  = (red[0][0] + red[1][0]) + (red[2][0] + red[3][0]);
        Spp = (red[0][1] + red[1][1]) + (red[2][1] + red[3][1]);
        St  = (red[0][2] + red[1][2]) + (red[2][2] + red[3][2]);
        Stt = (red[0][3] + red[1][3]) + (red[2][3] + red[3][3]);
        Spt = (red[0][4] + red[1][4]) + (red[2][4] + red[3][4]);
        fM  = (red[0][5] + red[1][5]) + (red[2][5] + red[3][5]);

        const float invH = 1.0f / NH;
        const float mp = Sp * invH;
        const float mt = St * invH;
        const float varp = (Spp - Sp * Sp * invH) * (1.0f / (NH - 1));
        const float vart = (Stt - St * St * invH) * (1.0f / (NH - 1));
        const float sdp = sqrtf(fmaxf(varp, 0.f)) + 1e-6f;
        const float sdt = sqrtf(fmaxf(vart, 0.f)) + 1e-6f;
        const float cov = Spt * invH - mp * mt;
        const float corr = cov / (sdp * sdt);

        const float sse = (Spp - 2.f * Spt) + Stt;

        float c = sse * (0.5f / ((float)NB * (float)NH))
                - fM  * (0.25f / ((float)NB * (float)(NH - 1)))
                + (1.f - corr) * (0.125f / (float)NB);
        if (row == 0) c += 0.25f;   // the constant term of the affine form
        atomicAdd(out, c);
    }
}

extern "C" void kernel_launch(void* const* d_in, const int* in_sizes, int n_in,
                              void* d_out, int out_size, void* d_ws, size_t ws_size,
                              hipStream_t stream) {
    const float* pred = (const float*)d_in[0];
    const float* targ = (const float*)d_in[1];
    float* out = (float*)d_out;

    hipMemsetAsync(out, 0, sizeof(float), stream);
    row_loss_kernel<<<NB, TPB, 0, stream>>>(pred, targ, out);
}

// Round 7
// 50.016 us; speedup vs baseline: 2.4831x; 2.4831x over previous
//
#include <hip/hip_runtime.h>
#include <math.h>

#define NB 8192
#define NH 4096
#define TPB1 1024
#define ROWS 4                       // rows per block, parallel (one per 256-thread group)
#define NBLK1 (NB / ROWS)            // 2048
#define ITERS ((NH / 4) / 256)       // 4
#define RTPB 512                     // reducer threads
#define RPT (NBLK1 / RTPB)           // 4 float4s per reducer thread

// Kernel 1: 2048 blocks x 1024 threads. Each 256-thread group handles one row
// (same coalescing as the proven 256-thread kernel). Per-block output is the
// combined partial over its 4 rows: { sum sse, sum M, sum (1-corr)/2, 0 }.
__global__ __launch_bounds__(TPB1) void row_stats_kernel(
    const float* __restrict__ pred, const float* __restrict__ targ,
    float4* __restrict__ ws4)
{
    const int tid  = threadIdx.x;
    const int sub  = tid >> 8;          // which of the 4 rows
    const int stid = tid & 255;         // index within the row group
    const int lane = tid & 63;
    const int wave = tid >> 6;          // 0..15; row r owns waves 4r..4r+3
    const int row  = blockIdx.x * ROWS + sub;

    const float* p = pred + (size_t)row * NH;
    const float* t = targ + (size_t)row * NH;
    const float4* p4 = (const float4*)p;
    const float4* t4 = (const float4*)t;

    // Hoist all loads: 8 outstanding float4 loads per thread (MLP).
    float4 pv[ITERS], tv[ITERS];
#pragma unroll
    for (int it = 0; it < ITERS; ++it) {
        pv[it] = p4[it * 256 + stid];
        tv[it] = t4[it * 256 + stid];
    }

    float Sp = 0.f, Spp = 0.f, St = 0.f, Stt = 0.f, Spt = 0.f;
    int M = 0;

#pragma unroll
    for (int it = 0; it < ITERS; ++it) {
        const int q = it * 256 + stid;   // float4 index within the row
        const float4 P = pv[it];
        const float4 T = tv[it];

        Sp  += (P.x + P.y) + (P.z + P.w);
        St  += (T.x + T.y) + (T.z + T.w);
        Spp += (P.x * P.x + P.y * P.y) + (P.z * P.z + P.w * P.w);
        Stt += (T.x * T.x + T.y * T.y) + (T.z * T.z + T.w * T.w);
        Spt += (P.x * T.x + P.y * T.y) + (P.z * T.z + P.w * T.w);

        // prev element (index 4q-1): previous lane's .w; lane 0 re-loads
        // (L1/L2-hit). Waves never span rows, so shfl stays within the row.
        float pprev = __shfl_up(P.w, 1);
        float tprev = __shfl_up(T.w, 1);
        if (lane == 0 && q > 0) { pprev = p[4 * q - 1]; tprev = t[4 * q - 1]; }

        if (q > 0) {
            const float dp = P.x - pprev, dt = T.x - tprev;
            M += (dt == 0.f) | (dp * dt > 0.f);
        }
        {
            const float dp1 = P.y - P.x, dt1 = T.y - T.x;
            M += (dt1 == 0.f) | (dp1 * dt1 > 0.f);
            const float dp2 = P.z - P.y, dt2 = T.z - T.y;
            M += (dt2 == 0.f) | (dp2 * dt2 > 0.f);
            const float dp3 = P.w - P.z, dt3 = T.w - T.z;
            M += (dt3 == 0.f) | (dp3 * dt3 > 0.f);
        }
    }

    // 64-lane wave reduce.
    float fM = (float)M;
#pragma unroll
    for (int off = 32; off > 0; off >>= 1) {
        Sp  += __shfl_down(Sp, off);
        Spp += __shfl_down(Spp, off);
        St  += __shfl_down(St, off);
        Stt += __shfl_down(Stt, off);
        Spt += __shfl_down(Spt, off);
        fM  += __shfl_down(fM, off);
    }

    __shared__ float red[16][6];
    __shared__ float part[ROWS][3];
    if (lane == 0) {
        red[wave][0] = Sp;  red[wave][1] = Spp; red[wave][2] = St;
        red[wave][3] = Stt; red[wave][4] = Spt; red[wave][5] = fM;
    }
    __syncthreads();

    // Threads 0..3 each finish one row's stats in parallel.
    if (tid < ROWS) {
        const int w0 = tid * 4;
        Sp  = (red[w0][0] + red[w0+1][0]) + (red[w0+2][0] + red[w0+3][0]);
        Spp = (red[w0][1] + red[w0+1][1]) + (red[w0+2][1] + red[w0+3][1]);
        St  = (red[w0][2] + red[w0+1][2]) + (red[w0+2][2] + red[w0+3][2]);
        Stt = (red[w0][3] + red[w0+1][3]) + (red[w0+2][3] + red[w0+3][3]);
        Spt = (red[w0][4] + red[w0+1][4]) + (red[w0+2][4] + red[w0+3][4]);
        fM  = (red[w0][5] + red[w0+1][5]) + (red[w0+2][5] + red[w0+3][5]);

        const float invH = 1.0f / NH;
        const float mp = Sp * invH;
        const float mt = St * invH;
        const float varp = (Spp - Sp * Sp * invH) * (1.0f / (NH - 1));
        const float vart = (Stt - St * St * invH) * (1.0f / (NH - 1));
        const float sdp = sqrtf(fmaxf(varp, 0.f)) + 1e-6f;
        const float sdt = sqrtf(fmaxf(vart, 0.f)) + 1e-6f;
        const float cov = Spt * invH - mp * mt;
        const float corr = cov / (sdp * sdt);

        part[tid][0] = (Spp - 2.f * Spt) + Stt;
        part[tid][1] = fM;
        part[tid][2] = (1.f - corr) * 0.5f;
    }
    __syncthreads();
    if (tid == 0) {
        float4 o;
        o.x = (part[0][0] + part[1][0]) + (part[2][0] + part[3][0]);
        o.y = (part[0][1] + part[1][1]) + (part[2][1] + part[3][1]);
        o.z = (part[0][2] + part[1][2]) + (part[2][2] + part[3][2]);
        o.w = 0.f;
        ws4[blockIdx.x] = o;
    }
}

// Kernel 2: reduce 2048 float4 partials (32 KB). All loads hoisted.
__global__ __launch_bounds__(RTPB) void final_reduce_kernel(
    const float4* __restrict__ ws4, float* __restrict__ out)
{
    const int tid = threadIdx.x;

    float4 v[RPT];
#pragma unroll
    for (int i = 0; i < RPT; ++i)
        v[i] = ws4[i * RTPB + tid];

    double s_mse = 0.0, s_match = 0.0, s_corr = 0.0;
#pragma unroll
    for (int i = 0; i < RPT; ++i) {
        s_mse   += (double)v[i].x;
        s_match += (double)v[i].y;
        s_corr  += (double)v[i].z;
    }
#pragma unroll
    for (int off = 32; off > 0; off >>= 1) {
        s_mse   += __shfl_down(s_mse, off);
        s_match += __shfl_down(s_match, off);
        s_corr  += __shfl_down(s_corr, off);
    }
    __shared__ double red[8][3];
    const int wave = tid >> 6;
    const int lane = tid & 63;
    if (lane == 0) {
        red[wave][0] = s_mse; red[wave][1] = s_match; red[wave][2] = s_corr;
    }
    __syncthreads();
    if (tid == 0) {
        s_mse = 0.0; s_match = 0.0; s_corr = 0.0;
#pragma unroll
        for (int w = 0; w < 8; ++w) {
            s_mse   += red[w][0];
            s_match += red[w][1];
            s_corr  += red[w][2];
        }
        const double mse       = s_mse / ((double)NB * (double)NH);
        const double dir_loss  = 1.0 - s_match / ((double)NB * (double)(NH - 1));
        const double corr_loss = s_corr / (double)NB;
        out[0] = (float)(0.5 * mse + 0.25 * (dir_loss + corr_loss));
    }
}

extern "C" void kernel_launch(void* const* d_in, const int* in_sizes, int n_in,
                              void* d_out, int out_size, void* d_ws, size_t ws_size,
                              hipStream_t stream) {
    const float* pred = (const float*)d_in[0];
    const float* targ = (const float*)d_in[1];
    float4* ws4 = (float4*)d_ws;   // 2048 * 16 B = 32 KB
    float* out  = (float*)d_out;

    row_stats_kernel<<<NBLK1, TPB1, 0, stream>>>(pred, targ, ws4);
    final_reduce_kernel<<<1, RTPB, 0, stream>>>(ws4, out);
}